// Round 1
// baseline (591.733 us; speedup 1.0000x reference)
//
#include <hip/hip_runtime.h>
#include <hip/hip_bf16.h>
#include <math.h>

#define NF   128   // F
#define NPH  64    // PH
#define NP   8     // P
#define ND   4     // D
#define NH   128   // H
#define NC   10    // C

typedef __bf16 bf16;
typedef __attribute__((ext_vector_type(8))) __bf16 bf16x8;
typedef __attribute__((ext_vector_type(4))) float f32x4;

__device__ __forceinline__ float gelu_exact(float x) {
    return 0.5f * x * (1.0f + erff(x * 0.70710678118654752f));
}

// ---------------------------------------------------------------------------
// K1: pp = x@W_proj.T + b_proj (store bf16);  h = gelu(x@W_x.T + b_x) (f32)
// Tile: 64 nodes x 96 channels per block, K=128 staged in two 64-halves.
// LDS: x_t[64][68] + w_t[96][68] f32 = 43.5 KB  (pads keep <=2-way conflicts)
// ---------------------------------------------------------------------------
__global__ __launch_bounds__(256) void k_proj(
    const float* __restrict__ x,
    const float* __restrict__ Wproj, const float* __restrict__ bproj,
    const float* __restrict__ Wx,    const float* __restrict__ bx,
    bf16* __restrict__ pp, float* __restrict__ h, int N)
{
    __shared__ float x_t[64][68];
    __shared__ float w_t[96][68];
    const int n0  = blockIdx.x * 64;
    const int ct  = blockIdx.y;            // channel tile: [ct*96, ct*96+96)
    const int tid = threadIdx.x;
    const int tr  = tid >> 4, tc = tid & 15;

    float acc[4][6];
    #pragma unroll
    for (int i = 0; i < 4; ++i)
        #pragma unroll
        for (int j = 0; j < 6; ++j) acc[i][j] = 0.f;

    for (int kh = 0; kh < 2; ++kh) {
        const int k0 = kh * 64;
        __syncthreads();
        // stage x: 64 rows x 64 cols = 1024 float4
        #pragma unroll
        for (int r = 0; r < 4; ++r) {
            int id  = r * 256 + tid;
            int row = id >> 4;
            int c4  = id & 15;
            float4 v = make_float4(0.f, 0.f, 0.f, 0.f);
            if (n0 + row < N)
                v = *(const float4*)&x[(size_t)(n0 + row) * NF + k0 + c4 * 4];
            *(float4*)&x_t[row][c4 * 4] = v;
        }
        // stage w: 96 rows x 64 cols = 1536 float4
        #pragma unroll
        for (int r = 0; r < 6; ++r) {
            int id  = r * 256 + tid;
            int row = id >> 4;
            int c4  = id & 15;
            int ch  = ct * 96 + row;
            const float* wsrc = (ch < NPH) ? &Wproj[(size_t)ch * NF]
                                           : &Wx[(size_t)(ch - NPH) * NF];
            *(float4*)&w_t[row][c4 * 4] = *(const float4*)&wsrc[k0 + c4 * 4];
        }
        __syncthreads();
        for (int k = 0; k < 64; k += 4) {
            float4 xa[4], wb[6];
            #pragma unroll
            for (int i = 0; i < 4; ++i) xa[i] = *(float4*)&x_t[tr * 4 + i][k];
            #pragma unroll
            for (int j = 0; j < 6; ++j) wb[j] = *(float4*)&w_t[j * 16 + tc][k];
            #pragma unroll
            for (int i = 0; i < 4; ++i)
                #pragma unroll
                for (int j = 0; j < 6; ++j)
                    acc[i][j] += xa[i].x * wb[j].x + xa[i].y * wb[j].y +
                                 xa[i].z * wb[j].z + xa[i].w * wb[j].w;
        }
    }
    #pragma unroll
    for (int i = 0; i < 4; ++i) {
        int n = n0 + tr * 4 + i;
        if (n >= N) continue;
        #pragma unroll
        for (int j = 0; j < 6; ++j) {
            int ch = ct * 96 + j * 16 + tc;
            float v = acc[i][j];
            if (ch < NPH) {
                v += bproj[ch];
                pp[(size_t)n * NPH + ch] = (bf16)v;
            } else {
                int hc = ch - NPH;
                h[(size_t)n * NH + hc] = gelu_exact(v + bx[hc]);
            }
        }
    }
}

// ---------------------------------------------------------------------------
// K2: per node-pair (2 nodes, 16 path-rows):
//   pi = gelu(path @ W_path.T + b_path), att = softmax(h . pi), agg = att . pi
//   aggbuf = 0.5*(agg + h)
// 4 waves/block; wave w owns h-tiles {2w,2w+1}; B-fragments hoisted to VGPRs.
// path staged to LDS bf16 with pitch 264 (bank-friendly for ds_read_b128).
// ---------------------------------------------------------------------------
__global__ __launch_bounds__(256) void k_path(
    const bf16* __restrict__ pp, const float* __restrict__ h,
    const float* __restrict__ Wpath, const float* __restrict__ bpath,
    const int* __restrict__ index, float* __restrict__ aggbuf,
    int N, int npairs)
{
    __shared__ alignas(16) unsigned short path_s[16 * 264];  // bf16 bits
    __shared__ float h_s[2][128];
    __shared__ float s_red[4][16];

    const int tid = threadIdx.x;
    const int w   = tid >> 6;          // wave 0..3
    const int l   = tid & 63;
    const int c   = l & 15;            // col within 16x16 tile
    const int g   = l >> 4;            // k-group / row-quad group
    const int nl  = g >> 1;            // local node (0/1) of this lane's rows
    const bool hi_half = (g & 1);

    // hoist B fragments: B[k][n] = W_path[n][k]; lane reads row h=base+c, 8 contiguous k
    bf16x8 bfrag[2][8];
    #pragma unroll
    for (int ht = 0; ht < 2; ++ht) {
        int hg = (w * 2 + ht) * 16 + c;
        #pragma unroll
        for (int ks = 0; ks < 8; ++ks) {
            int k = ks * 32 + g * 8;
            const float* src = &Wpath[(size_t)hg * 256 + k];
            float4 lo = *(const float4*)src;
            float4 hv = *(const float4*)(src + 4);
            bf16x8 b;
            b[0] = (bf16)lo.x; b[1] = (bf16)lo.y; b[2] = (bf16)lo.z; b[3] = (bf16)lo.w;
            b[4] = (bf16)hv.x; b[5] = (bf16)hv.y; b[6] = (bf16)hv.z; b[7] = (bf16)hv.w;
            bfrag[ht][ks] = b;
        }
    }
    const float bp0 = bpath[(w * 2 + 0) * 16 + c];
    const float bp1 = bpath[(w * 2 + 1) * 16 + c];

    for (int pair = blockIdx.x; pair < npairs; pair += gridDim.x) {
        const int n0 = pair * 2;
        __syncthreads();   // protect previous iteration's LDS reads

        // stage path: 16 rows x 256 bf16 = 512 x 16B chunks, 2 rounds
        #pragma unroll
        for (int rr = 0; rr < 2; ++rr) {
            int id  = rr * 256 + tid;
            int row = id >> 5;         // 32 chunks per row
            int cc  = id & 31;
            int d   = cc >> 3, q = cc & 7;
            int nn  = row >> 3, p = row & 7;
            int idx = index[(size_t)(n0 + nn) * (NP * ND) + p * ND + d];
            const int4* src = (const int4*)((const unsigned short*)pp +
                                            (size_t)idx * NPH + q * 8);
            *(int4*)&path_s[row * 264 + d * 64 + q * 8] = *src;
        }
        // stage h rows for the 2 nodes (1 KB)
        if (tid < 64) {
            int node = tid >> 5, q = tid & 31;
            *(float4*)&h_s[node][q * 4] =
                *(const float4*)&h[(size_t)(n0 + node) * NH + q * 4];
        }
        __syncthreads();

        // MFMA: rows = 16 path-rows, cols = this wave's 32 h's
        f32x4 acc0 = {0.f, 0.f, 0.f, 0.f};
        f32x4 acc1 = {0.f, 0.f, 0.f, 0.f};
        #pragma unroll
        for (int ks = 0; ks < 8; ++ks) {
            int koff = ks * 32 + g * 8;
            bf16x8 a = *reinterpret_cast<const bf16x8*>(&path_s[c * 264 + koff]);
            acc0 = __builtin_amdgcn_mfma_f32_16x16x32_bf16(a, bfrag[0][ks], acc0, 0, 0, 0);
            acc1 = __builtin_amdgcn_mfma_f32_16x16x32_bf16(a, bfrag[1][ks], acc1, 0, 0, 0);
        }

        // epilogue. lane holds rows m = g*4+i, cols h0=w*32+c, h1=w*32+16+c
        const float hv0 = h_s[nl][w * 32 + c];
        const float hv1 = h_s[nl][w * 32 + 16 + c];
        float pi0[4], pi1[4], sp[4];
        #pragma unroll
        for (int i = 0; i < 4; ++i) {
            pi0[i] = gelu_exact(acc0[i] + bp0);
            pi1[i] = gelu_exact(acc1[i] + bp1);
            sp[i]  = hv0 * pi0[i] + hv1 * pi1[i];
        }
        // reduce over the 16 cols (lanes sharing g)
        #pragma unroll
        for (int off = 1; off < 16; off <<= 1)
            #pragma unroll
            for (int i = 0; i < 4; ++i) sp[i] += __shfl_xor(sp[i], off, 64);
        if (c < 4) {
            float v = (c == 0) ? sp[0] : (c == 1) ? sp[1] : (c == 2) ? sp[2] : sp[3];
            s_red[w][g * 4 + c] = v;
        }
        __syncthreads();

        // total scores + softmax for this lane's node
        float s_tot[8];
        #pragma unroll
        for (int p = 0; p < 8; ++p) {
            int row = nl * 8 + p;
            s_tot[p] = s_red[0][row] + s_red[1][row] + s_red[2][row] + s_red[3][row];
        }
        float m = s_tot[0];
        #pragma unroll
        for (int p = 1; p < 8; ++p) m = fmaxf(m, s_tot[p]);
        float e[8], den = 0.f;
        #pragma unroll
        for (int p = 0; p < 8; ++p) { e[p] = __expf(s_tot[p] - m); den += e[p]; }
        const float inv = 1.0f / den;

        // agg = sum_p att[p]*pi[p][h]; this lane contributes 4 p's
        float pa0 = 0.f, pa1 = 0.f;
        #pragma unroll
        for (int i = 0; i < 4; ++i) {
            float a = hi_half ? e[4 + i] : e[i];
            pa0 += a * pi0[i];
            pa1 += a * pi1[i];
        }
        pa0 = (pa0 + __shfl_xor(pa0, 16, 64)) * inv;
        pa1 = (pa1 + __shfl_xor(pa1, 16, 64)) * inv;

        if (!hi_half) {
            int n = n0 + nl;
            aggbuf[(size_t)n * NH + w * 32 + c]      = 0.5f * (pa0 + hv0);
            aggbuf[(size_t)n * NH + w * 32 + 16 + c] = 0.5f * (pa1 + hv1);
        }
    }
}

// ---------------------------------------------------------------------------
// Edge pipeline: histogram -> scan -> scatter (counting sort by src)
// ---------------------------------------------------------------------------
__global__ void k_hist(const int* __restrict__ esrc, int* __restrict__ count, int E) {
    int i = blockIdx.x * 256 + threadIdx.x;
    if (i < E) atomicAdd(&count[esrc[i]], 1);
}

__global__ __launch_bounds__(1024) void k_scan(
    const int* __restrict__ count, int* __restrict__ base,
    int* __restrict__ cursor, int N, int E)
{
    __shared__ int sums[1024];
    const int tid = threadIdx.x;
    const int chunk = (N + 1023) >> 10;
    int lo = tid * chunk;
    int hi = lo + chunk; if (hi > N) hi = N;
    int s = 0;
    for (int i = lo; i < hi; ++i) s += count[i];
    sums[tid] = s;
    __syncthreads();
    for (int off = 1; off < 1024; off <<= 1) {
        int v = (tid >= off) ? sums[tid - off] : 0;
        __syncthreads();
        sums[tid] += v;
        __syncthreads();
    }
    int run = sums[tid] - s;   // exclusive prefix
    for (int i = lo; i < hi; ++i) {
        base[i] = run; cursor[i] = run;
        run += count[i];
    }
    if (tid == 1023) base[N] = E;
}

__global__ void k_scatter(const int* __restrict__ esrc, const int* __restrict__ edst,
                          int* __restrict__ cursor, int* __restrict__ sdst, int E) {
    int i = blockIdx.x * 256 + threadIdx.x;
    if (i < E) {
        int pos = atomicAdd(&cursor[esrc[i]], 1);
        sdst[pos] = edst[i];
    }
}

// ---------------------------------------------------------------------------
// Transpose W_A [H,N] f32 -> M [N,H] bf16
// ---------------------------------------------------------------------------
__global__ __launch_bounds__(256) void k_transpose(
    const float* __restrict__ WA, bf16* __restrict__ M, int N)
{
    __shared__ float t[128][65];
    const int n0  = blockIdx.x * 64;
    const int tid = threadIdx.x;
    const int w = tid >> 6, l = tid & 63;
    #pragma unroll
    for (int rep = 0; rep < 32; ++rep) {
        int hh = rep * 4 + w;
        int n  = n0 + l;
        t[hh][l] = (n < N) ? WA[(size_t)hh * N + n] : 0.f;
    }
    __syncthreads();
    #pragma unroll
    for (int rep = 0; rep < 32; ++rep) {
        int n_l = rep * 2 + (tid >> 7);
        int n   = n0 + n_l;
        if (n < N) M[(size_t)n * NH + (tid & 127)] = (bf16)t[tid & 127][n_l];
    }
}

// ---------------------------------------------------------------------------
// K3: A_x row-gather (sorted, coalesced 256B reads of bf16 M) + fused finale:
//   val = aggbuf + 0.5*(A_x + b_A); out = gelu(val) @ W_end.T + b_end
// One wave per node, lane l owns h = {2l, 2l+1}.
// ---------------------------------------------------------------------------
__global__ __launch_bounds__(256) void k_spmm_out(
    const bf16* __restrict__ Mb, const int* __restrict__ base,
    const int* __restrict__ sdst, const float* __restrict__ aggbuf,
    const float* __restrict__ bA, const float* __restrict__ Wend,
    const float* __restrict__ bend, float* __restrict__ out, int N)
{
    __shared__ float wend_s[NC][128];
    __shared__ float bend_s[NC];
    const int tid = threadIdx.x;
    for (int id = tid; id < NC * 128; id += 256) wend_s[id >> 7][id & 127] = Wend[id];
    if (tid < NC) bend_s[tid] = bend[tid];
    __syncthreads();

    const int w = tid >> 6, l = tid & 63;
    const int n = blockIdx.x * 4 + w;
    if (n >= N) return;

    const int b0 = base[n], b1 = base[n + 1];
    float a0 = 0.f, a1 = 0.f;
    int j = b0;
    for (; j + 4 <= b1; j += 4) {
        int d0 = sdst[j + 0], d1 = sdst[j + 1], d2 = sdst[j + 2], d3 = sdst[j + 3];
        unsigned v0 = ((const unsigned*)((const unsigned short*)Mb + (size_t)d0 * NH))[l];
        unsigned v1 = ((const unsigned*)((const unsigned short*)Mb + (size_t)d1 * NH))[l];
        unsigned v2 = ((const unsigned*)((const unsigned short*)Mb + (size_t)d2 * NH))[l];
        unsigned v3 = ((const unsigned*)((const unsigned short*)Mb + (size_t)d3 * NH))[l];
        a0 += __uint_as_float(v0 << 16) + __uint_as_float(v1 << 16) +
              __uint_as_float(v2 << 16) + __uint_as_float(v3 << 16);
        a1 += __uint_as_float(v0 & 0xffff0000u) + __uint_as_float(v1 & 0xffff0000u) +
              __uint_as_float(v2 & 0xffff0000u) + __uint_as_float(v3 & 0xffff0000u);
    }
    for (; j < b1; ++j) {
        int d = sdst[j];
        unsigned v = ((const unsigned*)((const unsigned short*)Mb + (size_t)d * NH))[l];
        a0 += __uint_as_float(v << 16);
        a1 += __uint_as_float(v & 0xffff0000u);
    }

    float2 ag = *(const float2*)&aggbuf[(size_t)n * NH + 2 * l];
    float v0 = ag.x + 0.5f * (a0 + bA[2 * l]);
    float v1 = ag.y + 0.5f * (a1 + bA[2 * l + 1]);
    float g0 = gelu_exact(v0), g1 = gelu_exact(v1);

    float part[NC];
    #pragma unroll
    for (int cc = 0; cc < NC; ++cc)
        part[cc] = g0 * wend_s[cc][2 * l] + g1 * wend_s[cc][2 * l + 1];
    #pragma unroll
    for (int off = 1; off < 64; off <<= 1)
        #pragma unroll
        for (int cc = 0; cc < NC; ++cc) part[cc] += __shfl_xor(part[cc], off, 64);

    float r = part[0];
    #pragma unroll
    for (int cc = 1; cc < NC; ++cc) r = (l == cc) ? part[cc] : r;
    if (l < NC) out[(size_t)n * NC + l] = r + bend_s[l];
}

// ---------------------------------------------------------------------------
extern "C" void kernel_launch(void* const* d_in, const int* in_sizes, int n_in,
                              void* d_out, int out_size, void* d_ws, size_t ws_size,
                              hipStream_t stream)
{
    const float* x     = (const float*)d_in[0];
    const float* Wproj = (const float*)d_in[1];
    const float* bproj = (const float*)d_in[2];
    const float* Wx    = (const float*)d_in[3];
    const float* bx    = (const float*)d_in[4];
    const float* Wpath = (const float*)d_in[5];
    const float* bpath = (const float*)d_in[6];
    const float* WA    = (const float*)d_in[7];
    const float* bA    = (const float*)d_in[8];
    const float* Wend  = (const float*)d_in[9];
    const float* bend  = (const float*)d_in[10];
    const int*   index = (const int*)d_in[11];
    const int*   eidx  = (const int*)d_in[12];

    const int N = in_sizes[0] / NF;
    const int E = in_sizes[12] / 2;
    const int* esrc = eidx;
    const int* edst = eidx + E;

    char* p = (char*)d_ws;
    auto alloc = [&](size_t bytes) {
        char* r = p;
        p += (bytes + 255) & ~(size_t)255;
        return r;
    };
    bf16*  pp     = (bf16*)alloc((size_t)N * NPH * sizeof(bf16));
    float* h      = (float*)alloc((size_t)N * NH * sizeof(float));
    float* aggbuf = (float*)alloc((size_t)N * NH * sizeof(float));
    bf16*  Mb     = (bf16*)alloc((size_t)N * NH * sizeof(bf16));
    int*   count  = (int*)alloc((size_t)N * sizeof(int));
    int*   base   = (int*)alloc((size_t)(N + 1) * sizeof(int));
    int*   cursor = (int*)alloc((size_t)N * sizeof(int));
    int*   sdst   = (int*)alloc((size_t)E * sizeof(int));

    hipMemsetAsync(count, 0, (size_t)N * sizeof(int), stream);
    k_hist<<<(E + 255) / 256, 256, 0, stream>>>(esrc, count, E);
    k_scan<<<1, 1024, 0, stream>>>(count, base, cursor, N, E);
    k_scatter<<<(E + 255) / 256, 256, 0, stream>>>(esrc, edst, cursor, sdst, E);
    k_transpose<<<(N + 63) / 64, 256, 0, stream>>>(WA, Mb, N);
    k_proj<<<dim3((N + 63) / 64, 2), 256, 0, stream>>>(x, Wproj, bproj, Wx, bx, pp, h, N);
    const int npairs = N / 2;
    k_path<<<2048, 256, 0, stream>>>(pp, h, Wpath, bpath, index, aggbuf, N, npairs);
    k_spmm_out<<<(N + 3) / 4, 256, 0, stream>>>(Mb, base, sdst, aggbuf, bA, Wend, bend,
                                                (float*)d_out, N);
}

// Round 2
// 564.489 us; speedup vs baseline: 1.0483x; 1.0483x over previous
//
#include <hip/hip_runtime.h>
#include <hip/hip_bf16.h>
#include <math.h>

#define NF   128   // F
#define NPH  64    // PH
#define NP   8     // P
#define ND   4     // D
#define NH   128   // H
#define NC   10    // C

typedef __bf16 bf16;
typedef __attribute__((ext_vector_type(4))) __bf16 bf16x4;
typedef __attribute__((ext_vector_type(8))) __bf16 bf16x8;
typedef __attribute__((ext_vector_type(4))) float f32x4;

// fast exact-erf GELU: Abramowitz-Stegun 7.1.26, |eps|<=1.5e-7
__device__ __forceinline__ float gelu_fast(float x) {
    float z = fabsf(x) * 0.70710678118654752f;
    float t = 1.0f / (1.0f + 0.3275911f * z);
    float poly = t * (0.254829592f + t * (-0.284496736f + t * (1.421413741f +
                 t * (-1.453152027f + t * 1.061405429f))));
    float erfv = 1.0f - poly * __expf(-z * z);
    float s = copysignf(erfv, x);
    return 0.5f * x * (1.0f + s);
}

#define GLOAD_LDS16(g, l)                                                     \
    __builtin_amdgcn_global_load_lds(                                         \
        (const __attribute__((address_space(1))) unsigned int*)(g),           \
        (__attribute__((address_space(3))) unsigned int*)(l), 16, 0, 0)

__device__ __forceinline__ bf16x8 cvt8(float4 a, float4 b) {
    bf16x8 r;
    r[0] = (bf16)a.x; r[1] = (bf16)a.y; r[2] = (bf16)a.z; r[3] = (bf16)a.w;
    r[4] = (bf16)b.x; r[5] = (bf16)b.y; r[6] = (bf16)b.z; r[7] = (bf16)b.w;
    return r;
}

// ---------------------------------------------------------------------------
// K1 (MFMA): pp = x@W_proj.T + b_proj (bf16); h = gelu(x@W_x.T + b_x) (f32)
// 64 nodes/block, 192 out channels; wave w owns col-tiles w*3..w*3+2.
// B (W rows) hoisted to VGPRs; x staged bf16 in LDS pitch 136 (conflict-free).
// ---------------------------------------------------------------------------
__global__ __launch_bounds__(256) void k_proj(
    const float* __restrict__ x,
    const float* __restrict__ Wproj, const float* __restrict__ bproj,
    const float* __restrict__ Wx,    const float* __restrict__ bx,
    bf16* __restrict__ pp, float* __restrict__ h, int N)
{
    __shared__ alignas(16) bf16 x_s[64 * 136];
    const int tid = threadIdx.x;
    const int w = tid >> 6, l = tid & 63;
    const int c = l & 15, g = l >> 4;

    bf16x8 bfr[3][4];
    float bias[3];
    #pragma unroll
    for (int t = 0; t < 3; ++t) {
        int ch = (w * 3 + t) * 16 + c;
        const float* wr = (ch < NPH) ? &Wproj[(size_t)ch * NF]
                                     : &Wx[(size_t)(ch - NPH) * NF];
        bias[t] = (ch < NPH) ? bproj[ch] : bx[ch - NPH];
        #pragma unroll
        for (int ks = 0; ks < 4; ++ks) {
            const float* src = wr + ks * 32 + g * 8;
            bfr[t][ks] = cvt8(*(const float4*)src, *(const float4*)(src + 4));
        }
    }

    const int n0 = blockIdx.x * 64;
    #pragma unroll
    for (int rr = 0; rr < 8; ++rr) {
        int id  = rr * 256 + tid;        // 2048 float4 chunks: 64 rows x 32
        int row = id >> 5, c4 = id & 31;
        float4 v = make_float4(0.f, 0.f, 0.f, 0.f);
        if (n0 + row < N) v = *(const float4*)&x[(size_t)(n0 + row) * NF + c4 * 4];
        bf16x4 o;
        o[0] = (bf16)v.x; o[1] = (bf16)v.y; o[2] = (bf16)v.z; o[3] = (bf16)v.w;
        *(bf16x4*)&x_s[row * 136 + c4 * 4] = o;
    }
    __syncthreads();

    f32x4 acc[4][3] = {};
    #pragma unroll
    for (int rt = 0; rt < 4; ++rt)
        #pragma unroll
        for (int ks = 0; ks < 4; ++ks) {
            bf16x8 a = *(const bf16x8*)&x_s[(rt * 16 + c) * 136 + ks * 32 + g * 8];
            #pragma unroll
            for (int t = 0; t < 3; ++t)
                acc[rt][t] = __builtin_amdgcn_mfma_f32_16x16x32_bf16(
                    a, bfr[t][ks], acc[rt][t], 0, 0, 0);
        }

    #pragma unroll
    for (int rt = 0; rt < 4; ++rt) {
        #pragma unroll
        for (int t = 0; t < 3; ++t) {
            int ch = (w * 3 + t) * 16 + c;
            #pragma unroll
            for (int i = 0; i < 4; ++i) {
                int n = n0 + rt * 16 + g * 4 + i;
                if (n >= N) continue;
                float v = acc[rt][t][i] + bias[t];
                if (ch < NPH) pp[(size_t)n * NPH + ch] = (bf16)v;
                else          h[(size_t)n * NH + (ch - NPH)] = gelu_fast(v);
            }
        }
    }
}

// ---------------------------------------------------------------------------
// K2: per round = 4 nodes (32 path rows):
//   pi = gelu(path @ W_path.T + b), att = softmax(h.pi), agg; aggbuf=0.5(agg+h)
// Staging via global_load_lds (linear LDS, q-XOR swizzle baked into global
// source; same XOR on ds_read side -> conflict-free b128).
// 3 barriers / 2 pairs (was 3 / pair).
// ---------------------------------------------------------------------------
__global__ __launch_bounds__(256) void k_path(
    const bf16* __restrict__ pp, const float* __restrict__ h,
    const float* __restrict__ Wpath, const float* __restrict__ bpath,
    const int* __restrict__ index, float* __restrict__ aggbuf,
    int N, int nrounds)
{
    __shared__ alignas(16) bf16 path_s[32 * 256];   // linear, swizzled content
    __shared__ float h_s[4][128];
    __shared__ float s_red[4][32];

    const int tid = threadIdx.x;
    const int w   = tid >> 6;
    const int l   = tid & 63;
    const int c   = l & 15;
    const int g   = l >> 4;
    const int nl  = g >> 1;            // local node (within a pair)
    const bool hi_half = (g & 1);

    // hoist B fragments (W_path cols for this wave's 2 h-tiles)
    bf16x8 bfrag[2][8];
    #pragma unroll
    for (int ht = 0; ht < 2; ++ht) {
        int hg = (w * 2 + ht) * 16 + c;
        #pragma unroll
        for (int ks = 0; ks < 8; ++ks) {
            const float* src = &Wpath[(size_t)hg * 256 + ks * 32 + g * 8];
            bfrag[ht][ks] = cvt8(*(const float4*)src, *(const float4*)(src + 4));
        }
    }
    const float bp0 = bpath[(w * 2 + 0) * 16 + c];
    const float bp1 = bpath[(w * 2 + 1) * 16 + c];

    for (int round = blockIdx.x; round < nrounds; round += gridDim.x) {
        const int n0 = round * 4;
        __syncthreads();   // protect prev round's path_s / s_red reads

        // stage: 1024 16B chunks (32 rows x 32), 4 per thread, direct to LDS.
        // physical chunk (row, cc) holds logical chunk (row, cc ^ (row&7)).
        #pragma unroll
        for (int rr = 0; rr < 4; ++rr) {
            int id  = rr * 256 + tid;
            int row = id >> 5;
            int cc  = id & 31;
            int ls  = cc ^ (row & 7);
            int d   = ls >> 3, q = ls & 7;
            int nn  = row >> 3, p = row & 7;
            int idx = index[(size_t)(n0 + nn) * (NP * ND) + p * ND + d];
            const bf16* src = pp + (size_t)idx * NPH + q * 8;
            GLOAD_LDS16(src, &path_s[id * 8]);
        }
        if (tid < 128) {
            int node = tid >> 5, q = tid & 31;
            *(float4*)&h_s[node][q * 4] =
                *(const float4*)&h[(size_t)(n0 + node) * NH + q * 4];
        }
        __syncthreads();

        // MFMA: row-tile rt covers rows rt*16..rt*16+15 (pair rt)
        f32x4 acc[2][2] = {};
        #pragma unroll
        for (int rt = 0; rt < 2; ++rt) {
            const int rowbase = (rt * 16 + c) * 256;
            #pragma unroll
            for (int ks = 0; ks < 8; ++ks) {
                int chunk = (ks * 4 + g) ^ (c & 7);     // read-side XOR
                bf16x8 a = *(const bf16x8*)&path_s[rowbase + chunk * 8];
                acc[rt][0] = __builtin_amdgcn_mfma_f32_16x16x32_bf16(
                    a, bfrag[0][ks], acc[rt][0], 0, 0, 0);
                acc[rt][1] = __builtin_amdgcn_mfma_f32_16x16x32_bf16(
                    a, bfrag[1][ks], acc[rt][1], 0, 0, 0);
            }
        }

        // epilogue part 1: pi = gelu(acc+b); partial scores -> s_red
        float pi[2][2][4];
        #pragma unroll
        for (int rt = 0; rt < 2; ++rt) {
            const float hv0 = h_s[rt * 2 + nl][w * 32 + c];
            const float hv1 = h_s[rt * 2 + nl][w * 32 + 16 + c];
            float sp[4];
            #pragma unroll
            for (int i = 0; i < 4; ++i) {
                pi[rt][0][i] = gelu_fast(acc[rt][0][i] + bp0);
                pi[rt][1][i] = gelu_fast(acc[rt][1][i] + bp1);
                sp[i] = hv0 * pi[rt][0][i] + hv1 * pi[rt][1][i];
            }
            #pragma unroll
            for (int off = 1; off < 16; off <<= 1)
                #pragma unroll
                for (int i = 0; i < 4; ++i) sp[i] += __shfl_xor(sp[i], off, 64);
            float v = (c == 0) ? sp[0] : (c == 1) ? sp[1] : (c == 2) ? sp[2] : sp[3];
            if (c < 4) s_red[w][rt * 16 + g * 4 + c] = v;
        }
        __syncthreads();

        // epilogue part 2: softmax + weighted aggregate + write
        #pragma unroll
        for (int rt = 0; rt < 2; ++rt) {
            const int rbase = rt * 16 + nl * 8;
            float st[8];
            #pragma unroll
            for (int p = 0; p < 8; ++p)
                st[p] = s_red[0][rbase + p] + s_red[1][rbase + p] +
                        s_red[2][rbase + p] + s_red[3][rbase + p];
            float m = st[0];
            #pragma unroll
            for (int p = 1; p < 8; ++p) m = fmaxf(m, st[p]);
            float e[8], den = 0.f;
            #pragma unroll
            for (int p = 0; p < 8; ++p) { e[p] = __expf(st[p] - m); den += e[p]; }
            const float inv = 1.0f / den;

            float pa0 = 0.f, pa1 = 0.f;
            #pragma unroll
            for (int i = 0; i < 4; ++i) {
                float a = hi_half ? e[4 + i] : e[i];
                pa0 += a * pi[rt][0][i];
                pa1 += a * pi[rt][1][i];
            }
            pa0 = (pa0 + __shfl_xor(pa0, 16, 64)) * inv;
            pa1 = (pa1 + __shfl_xor(pa1, 16, 64)) * inv;

            if (!hi_half) {
                int n = n0 + rt * 2 + nl;
                const float hv0 = h_s[rt * 2 + nl][w * 32 + c];
                const float hv1 = h_s[rt * 2 + nl][w * 32 + 16 + c];
                aggbuf[(size_t)n * NH + w * 32 + c]      = 0.5f * (pa0 + hv0);
                aggbuf[(size_t)n * NH + w * 32 + 16 + c] = 0.5f * (pa1 + hv1);
            }
        }
    }
}

// ---------------------------------------------------------------------------
// Edge pipeline: histogram -> scan -> scatter (counting sort by src)
// ---------------------------------------------------------------------------
__global__ void k_hist(const int* __restrict__ esrc, int* __restrict__ count, int E) {
    int i = blockIdx.x * 256 + threadIdx.x;
    if (i < E) atomicAdd(&count[esrc[i]], 1);
}

__global__ __launch_bounds__(1024) void k_scan(
    const int* __restrict__ count, int* __restrict__ base,
    int* __restrict__ cursor, int N, int E)
{
    __shared__ int sums[1024];
    const int tid = threadIdx.x;
    const int chunk = (N + 1023) >> 10;
    int lo = tid * chunk;
    int hi = lo + chunk; if (hi > N) hi = N;
    int s = 0;
    for (int i = lo; i < hi; ++i) s += count[i];
    sums[tid] = s;
    __syncthreads();
    for (int off = 1; off < 1024; off <<= 1) {
        int v = (tid >= off) ? sums[tid - off] : 0;
        __syncthreads();
        sums[tid] += v;
        __syncthreads();
    }
    int run = sums[tid] - s;   // exclusive prefix
    for (int i = lo; i < hi; ++i) {
        base[i] = run; cursor[i] = run;
        run += count[i];
    }
    if (tid == 1023) base[N] = E;
}

__global__ void k_scatter(const int* __restrict__ esrc, const int* __restrict__ edst,
                          int* __restrict__ cursor, int* __restrict__ sdst, int E) {
    int i = blockIdx.x * 256 + threadIdx.x;
    if (i < E) {
        int pos = atomicAdd(&cursor[esrc[i]], 1);
        sdst[pos] = edst[i];
    }
}

// ---------------------------------------------------------------------------
// Transpose W_A [H,N] f32 -> M [N,H] bf16
// ---------------------------------------------------------------------------
__global__ __launch_bounds__(256) void k_transpose(
    const float* __restrict__ WA, bf16* __restrict__ M, int N)
{
    __shared__ float t[128][65];
    const int n0  = blockIdx.x * 64;
    const int tid = threadIdx.x;
    const int w = tid >> 6, l = tid & 63;
    #pragma unroll
    for (int rep = 0; rep < 32; ++rep) {
        int hh = rep * 4 + w;
        int n  = n0 + l;
        t[hh][l] = (n < N) ? WA[(size_t)hh * N + n] : 0.f;
    }
    __syncthreads();
    #pragma unroll
    for (int rep = 0; rep < 32; ++rep) {
        int n_l = rep * 2 + (tid >> 7);
        int n   = n0 + n_l;
        if (n < N) M[(size_t)n * NH + (tid & 127)] = (bf16)t[tid & 127][n_l];
    }
}

// ---------------------------------------------------------------------------
// K3: A_x row-gather (sorted, 256B coalesced rows of bf16 M) + fused finale:
//   val = aggbuf + 0.5*(A_x + b_A); out = gelu(val) @ W_end.T + b_end
// One wave per node; 8-deep unrolled gather to hide L3 latency.
// ---------------------------------------------------------------------------
__global__ __launch_bounds__(256) void k_spmm_out(
    const bf16* __restrict__ Mb, const int* __restrict__ base,
    const int* __restrict__ sdst, const float* __restrict__ aggbuf,
    const float* __restrict__ bA, const float* __restrict__ Wend,
    const float* __restrict__ bend, float* __restrict__ out, int N)
{
    __shared__ float wend_s[NC][128];
    __shared__ float bend_s[NC];
    const int tid = threadIdx.x;
    for (int id = tid; id < NC * 128; id += 256) wend_s[id >> 7][id & 127] = Wend[id];
    if (tid < NC) bend_s[tid] = bend[tid];
    __syncthreads();

    const int w = tid >> 6, l = tid & 63;
    const int n = blockIdx.x * 4 + w;
    if (n >= N) return;

    const int b0 = base[n], b1 = base[n + 1];
    float a0 = 0.f, a1 = 0.f;
    int j = b0;
    for (; j + 8 <= b1; j += 8) {
        int d[8];
        #pragma unroll
        for (int k = 0; k < 8; ++k) d[k] = sdst[j + k];
        unsigned v[8];
        #pragma unroll
        for (int k = 0; k < 8; ++k)
            v[k] = ((const unsigned*)((const unsigned short*)Mb + (size_t)d[k] * NH))[l];
        #pragma unroll
        for (int k = 0; k < 8; ++k) {
            a0 += __uint_as_float(v[k] << 16);
            a1 += __uint_as_float(v[k] & 0xffff0000u);
        }
    }
    for (; j < b1; ++j) {
        int dd = sdst[j];
        unsigned v = ((const unsigned*)((const unsigned short*)Mb + (size_t)dd * NH))[l];
        a0 += __uint_as_float(v << 16);
        a1 += __uint_as_float(v & 0xffff0000u);
    }

    float2 ag = *(const float2*)&aggbuf[(size_t)n * NH + 2 * l];
    float v0 = ag.x + 0.5f * (a0 + bA[2 * l]);
    float v1 = ag.y + 0.5f * (a1 + bA[2 * l + 1]);
    float g0 = gelu_fast(v0), g1 = gelu_fast(v1);

    float part[NC];
    #pragma unroll
    for (int cc = 0; cc < NC; ++cc)
        part[cc] = g0 * wend_s[cc][2 * l] + g1 * wend_s[cc][2 * l + 1];
    #pragma unroll
    for (int off = 1; off < 64; off <<= 1)
        #pragma unroll
        for (int cc = 0; cc < NC; ++cc) part[cc] += __shfl_xor(part[cc], off, 64);

    float r = part[0];
    #pragma unroll
    for (int cc = 1; cc < NC; ++cc) r = (l == cc) ? part[cc] : r;
    if (l < NC) out[(size_t)n * NC + l] = r + bend_s[l];
}

// ---------------------------------------------------------------------------
extern "C" void kernel_launch(void* const* d_in, const int* in_sizes, int n_in,
                              void* d_out, int out_size, void* d_ws, size_t ws_size,
                              hipStream_t stream)
{
    const float* x     = (const float*)d_in[0];
    const float* Wproj = (const float*)d_in[1];
    const float* bproj = (const float*)d_in[2];
    const float* Wx    = (const float*)d_in[3];
    const float* bx    = (const float*)d_in[4];
    const float* Wpath = (const float*)d_in[5];
    const float* bpath = (const float*)d_in[6];
    const float* WA    = (const float*)d_in[7];
    const float* bA    = (const float*)d_in[8];
    const float* Wend  = (const float*)d_in[9];
    const float* bend  = (const float*)d_in[10];
    const int*   index = (const int*)d_in[11];
    const int*   eidx  = (const int*)d_in[12];

    const int N = in_sizes[0] / NF;
    const int E = in_sizes[12] / 2;
    const int* esrc = eidx;
    const int* edst = eidx + E;

    char* p = (char*)d_ws;
    auto alloc = [&](size_t bytes) {
        char* r = p;
        p += (bytes + 255) & ~(size_t)255;
        return r;
    };
    bf16*  pp     = (bf16*)alloc((size_t)N * NPH * sizeof(bf16));
    float* h      = (float*)alloc((size_t)N * NH * sizeof(float));
    float* aggbuf = (float*)alloc((size_t)N * NH * sizeof(float));
    bf16*  Mb     = (bf16*)alloc((size_t)N * NH * sizeof(bf16));
    int*   count  = (int*)alloc((size_t)N * sizeof(int));
    int*   base   = (int*)alloc((size_t)(N + 1) * sizeof(int));
    int*   cursor = (int*)alloc((size_t)N * sizeof(int));
    int*   sdst   = (int*)alloc((size_t)E * sizeof(int));

    hipMemsetAsync(count, 0, (size_t)N * sizeof(int), stream);
    k_hist<<<(E + 255) / 256, 256, 0, stream>>>(esrc, count, E);
    k_scan<<<1, 1024, 0, stream>>>(count, base, cursor, N, E);
    k_scatter<<<(E + 255) / 256, 256, 0, stream>>>(esrc, edst, cursor, sdst, E);
    k_transpose<<<(N + 63) / 64, 256, 0, stream>>>(WA, Mb, N);
    k_proj<<<(N + 63) / 64, 256, 0, stream>>>(x, Wproj, bproj, Wx, bx, pp, h, N);
    const int nrounds = N / 4;
    k_path<<<2500, 256, 0, stream>>>(pp, h, Wpath, bpath, index, aggbuf, N, nrounds);
    k_spmm_out<<<(N + 3) / 4, 256, 0, stream>>>(Mb, base, sdst, aggbuf, bA, Wend, bend,
                                                (float*)d_out, N);
}

// Round 3
// 437.365 us; speedup vs baseline: 1.3529x; 1.2907x over previous
//
#include <hip/hip_runtime.h>
#include <hip/hip_bf16.h>
#include <math.h>

#define NF   128   // F
#define NPH  64    // PH
#define NP   8     // P
#define ND   4     // D
#define NH   128   // H
#define NC   10    // C

typedef __bf16 bf16;
typedef __attribute__((ext_vector_type(4))) __bf16 bf16x4;
typedef __attribute__((ext_vector_type(8))) __bf16 bf16x8;
typedef __attribute__((ext_vector_type(4))) float f32x4;

// fast exact-erf GELU: Abramowitz-Stegun 7.1.25 (3-term), |eps|<=2.5e-5
__device__ __forceinline__ float gelu_fast(float x) {
    float z = fabsf(x) * 0.70710678118654752f;
    float t = 1.0f / (1.0f + 0.47047f * z);
    float poly = t * (0.3480242f + t * (-0.0958798f + t * 0.7478556f));
    float erfv = 1.0f - poly * __expf(-z * z);
    float s = copysignf(erfv, x);
    return 0.5f * x * (1.0f + s);
}

#define GLOAD_LDS16(g, l)                                                     \
    __builtin_amdgcn_global_load_lds(                                         \
        (const __attribute__((address_space(1))) unsigned int*)(g),           \
        (__attribute__((address_space(3))) unsigned int*)(l), 16, 0, 0)

__device__ __forceinline__ bf16x8 cvt8(float4 a, float4 b) {
    bf16x8 r;
    r[0] = (bf16)a.x; r[1] = (bf16)a.y; r[2] = (bf16)a.z; r[3] = (bf16)a.w;
    r[4] = (bf16)b.x; r[5] = (bf16)b.y; r[6] = (bf16)b.z; r[7] = (bf16)b.w;
    return r;
}

// ---------------------------------------------------------------------------
// K1 (MFMA): pp = x@W_proj.T + b_proj (bf16); h = gelu(x@W_x.T + b_x) (f32)
// ---------------------------------------------------------------------------
__global__ __launch_bounds__(256) void k_proj(
    const float* __restrict__ x,
    const float* __restrict__ Wproj, const float* __restrict__ bproj,
    const float* __restrict__ Wx,    const float* __restrict__ bx,
    bf16* __restrict__ pp, float* __restrict__ h, int N)
{
    __shared__ alignas(16) bf16 x_s[64 * 136];
    const int tid = threadIdx.x;
    const int w = tid >> 6, l = tid & 63;
    const int c = l & 15, g = l >> 4;

    bf16x8 bfr[3][4];
    float bias[3];
    #pragma unroll
    for (int t = 0; t < 3; ++t) {
        int ch = (w * 3 + t) * 16 + c;
        const float* wr = (ch < NPH) ? &Wproj[(size_t)ch * NF]
                                     : &Wx[(size_t)(ch - NPH) * NF];
        bias[t] = (ch < NPH) ? bproj[ch] : bx[ch - NPH];
        #pragma unroll
        for (int ks = 0; ks < 4; ++ks) {
            const float* src = wr + ks * 32 + g * 8;
            bfr[t][ks] = cvt8(*(const float4*)src, *(const float4*)(src + 4));
        }
    }

    const int n0 = blockIdx.x * 64;
    #pragma unroll
    for (int rr = 0; rr < 8; ++rr) {
        int id  = rr * 256 + tid;        // 2048 float4 chunks: 64 rows x 32
        int row = id >> 5, c4 = id & 31;
        float4 v = make_float4(0.f, 0.f, 0.f, 0.f);
        if (n0 + row < N) v = *(const float4*)&x[(size_t)(n0 + row) * NF + c4 * 4];
        bf16x4 o;
        o[0] = (bf16)v.x; o[1] = (bf16)v.y; o[2] = (bf16)v.z; o[3] = (bf16)v.w;
        *(bf16x4*)&x_s[row * 136 + c4 * 4] = o;
    }
    __syncthreads();

    f32x4 acc[4][3] = {};
    #pragma unroll
    for (int rt = 0; rt < 4; ++rt)
        #pragma unroll
        for (int ks = 0; ks < 4; ++ks) {
            bf16x8 a = *(const bf16x8*)&x_s[(rt * 16 + c) * 136 + ks * 32 + g * 8];
            #pragma unroll
            for (int t = 0; t < 3; ++t)
                acc[rt][t] = __builtin_amdgcn_mfma_f32_16x16x32_bf16(
                    a, bfr[t][ks], acc[rt][t], 0, 0, 0);
        }

    #pragma unroll
    for (int rt = 0; rt < 4; ++rt) {
        #pragma unroll
        for (int t = 0; t < 3; ++t) {
            int ch = (w * 3 + t) * 16 + c;
            #pragma unroll
            for (int i = 0; i < 4; ++i) {
                int n = n0 + rt * 16 + g * 4 + i;
                if (n >= N) continue;
                float v = acc[rt][t][i] + bias[t];
                if (ch < NPH) pp[(size_t)n * NPH + ch] = (bf16)v;
                else          h[(size_t)n * NH + (ch - NPH)] = gelu_fast(v);
            }
        }
    }
}

// ---------------------------------------------------------------------------
// K2: per round = 4 nodes (32 path rows). Double-buffered, software-pipelined:
//   top __syncthreads drains round-r stage; round-(r+G) stage issued
//   immediately; mid-round raw s_barrier drains only lgkm (s_red visibility),
//   leaving the next-round global_load_lds in flight under MFMA+epilogue.
// ---------------------------------------------------------------------------
__global__ __launch_bounds__(256) void k_path(
    const bf16* __restrict__ pp, const float* __restrict__ h,
    const float* __restrict__ Wpath, const float* __restrict__ bpath,
    const int* __restrict__ index, float* __restrict__ aggbuf,
    int N, int nrounds)
{
    __shared__ alignas(16) bf16 path_s[2][32 * 256];  // swizzled content
    __shared__ alignas(16) float h_s[2][4][128];
    __shared__ float s_red[4][32];

    const int tid = threadIdx.x;
    const int w   = tid >> 6;
    const int l   = tid & 63;
    const int c   = l & 15;
    const int g   = l >> 4;
    const int nl  = g >> 1;            // local node (within a pair)
    const bool hi_half = (g & 1);

    // hoist B fragments (W_path cols for this wave's 2 h-tiles)
    bf16x8 bfrag[2][8];
    #pragma unroll
    for (int ht = 0; ht < 2; ++ht) {
        int hg = (w * 2 + ht) * 16 + c;
        #pragma unroll
        for (int ks = 0; ks < 8; ++ks) {
            const float* src = &Wpath[(size_t)hg * 256 + ks * 32 + g * 8];
            bfrag[ht][ks] = cvt8(*(const float4*)src, *(const float4*)(src + 4));
        }
    }
    const float bp0 = bpath[(w * 2 + 0) * 16 + c];
    const float bp1 = bpath[(w * 2 + 1) * 16 + c];

    auto stage = [&](int round, int b) {
        const int n0 = round * 4;
        #pragma unroll
        for (int rr = 0; rr < 4; ++rr) {
            int id  = rr * 256 + tid;
            int row = id >> 5;
            int cc  = id & 31;
            int ls  = cc ^ (row & 7);      // source-side swizzle
            int d   = ls >> 3, q = ls & 7;
            int nn  = row >> 3, p = row & 7;
            int idx = index[(size_t)(n0 + nn) * (NP * ND) + p * ND + d];
            GLOAD_LDS16(pp + (size_t)idx * NPH + q * 8, &path_s[b][id * 8]);
        }
        if (tid < 128) {
            int node = tid >> 5, q = tid & 31;
            GLOAD_LDS16(&h[(size_t)(n0 + node) * NH + q * 4], &h_s[b][node][q * 4]);
        }
    };

    int r = blockIdx.x;
    const int G = gridDim.x;
    if (r < nrounds) stage(r, 0);
    int buf = 0;

    for (; r < nrounds; r += G) {
        const int n0 = r * 4;
        __syncthreads();                        // round-r stage complete
        if (r + G < nrounds) stage(r + G, buf ^ 1);   // prefetch next round

        // MFMA: row-tile rt covers rows rt*16..rt*16+15 (pair rt)
        f32x4 acc[2][2] = {};
        #pragma unroll
        for (int rt = 0; rt < 2; ++rt) {
            const int rowbase = (rt * 16 + c) * 256;
            #pragma unroll
            for (int ks = 0; ks < 8; ++ks) {
                int chunk = (ks * 4 + g) ^ (c & 7);     // read-side XOR
                bf16x8 a = *(const bf16x8*)&path_s[buf][rowbase + chunk * 8];
                acc[rt][0] = __builtin_amdgcn_mfma_f32_16x16x32_bf16(
                    a, bfrag[0][ks], acc[rt][0], 0, 0, 0);
                acc[rt][1] = __builtin_amdgcn_mfma_f32_16x16x32_bf16(
                    a, bfrag[1][ks], acc[rt][1], 0, 0, 0);
            }
        }

        // epilogue part 1: pi = gelu(acc+b); partial scores -> s_red
        float pi[2][2][4];
        #pragma unroll
        for (int rt = 0; rt < 2; ++rt) {
            const float hv0 = h_s[buf][rt * 2 + nl][w * 32 + c];
            const float hv1 = h_s[buf][rt * 2 + nl][w * 32 + 16 + c];
            float sp[4];
            #pragma unroll
            for (int i = 0; i < 4; ++i) {
                pi[rt][0][i] = gelu_fast(acc[rt][0][i] + bp0);
                pi[rt][1][i] = gelu_fast(acc[rt][1][i] + bp1);
                sp[i] = hv0 * pi[rt][0][i] + hv1 * pi[rt][1][i];
            }
            #pragma unroll
            for (int off = 1; off < 16; off <<= 1)
                #pragma unroll
                for (int i = 0; i < 4; ++i) sp[i] += __shfl_xor(sp[i], off, 64);
            float v = (c == 0) ? sp[0] : (c == 1) ? sp[1] : (c == 2) ? sp[2] : sp[3];
            if (c < 4) s_red[w][rt * 16 + g * 4 + c] = v;
        }

        // raw barrier: drain LDS ops only, keep global_load_lds in flight
        __builtin_amdgcn_sched_barrier(0);
        asm volatile("s_waitcnt lgkmcnt(0)" ::: "memory");
        __builtin_amdgcn_s_barrier();
        __builtin_amdgcn_sched_barrier(0);

        // epilogue part 2: softmax (lane computes its own 4 rows + partner)
        #pragma unroll
        for (int rt = 0; rt < 2; ++rt) {
            float st[4];
            #pragma unroll
            for (int i = 0; i < 4; ++i) {
                int row = rt * 16 + g * 4 + i;
                st[i] = s_red[0][row] + s_red[1][row] +
                        s_red[2][row] + s_red[3][row];
            }
            float m4 = fmaxf(fmaxf(st[0], st[1]), fmaxf(st[2], st[3]));
            float m  = fmaxf(m4, __shfl_xor(m4, 16, 64));
            float e[4], s4 = 0.f;
            #pragma unroll
            for (int i = 0; i < 4; ++i) { e[i] = __expf(st[i] - m); s4 += e[i]; }
            float den = s4 + __shfl_xor(s4, 16, 64);
            const float inv = 1.0f / den;

            float pa0 = 0.f, pa1 = 0.f;
            #pragma unroll
            for (int i = 0; i < 4; ++i) {
                pa0 += e[i] * pi[rt][0][i];
                pa1 += e[i] * pi[rt][1][i];
            }
            pa0 = (pa0 + __shfl_xor(pa0, 16, 64)) * inv;
            pa1 = (pa1 + __shfl_xor(pa1, 16, 64)) * inv;

            if (!hi_half) {
                int n = n0 + rt * 2 + nl;
                const float hv0 = h_s[buf][rt * 2 + nl][w * 32 + c];
                const float hv1 = h_s[buf][rt * 2 + nl][w * 32 + 16 + c];
                aggbuf[(size_t)n * NH + w * 32 + c]      = 0.5f * (pa0 + hv0);
                aggbuf[(size_t)n * NH + w * 32 + 16 + c] = 0.5f * (pa1 + hv1);
            }
        }
        buf ^= 1;
    }
}

// ---------------------------------------------------------------------------
// Edge pipeline: histogram -> 3-stage multi-block scan -> scatter
// ---------------------------------------------------------------------------
__global__ void k_hist(const int* __restrict__ esrc, int* __restrict__ count, int E) {
    int i = blockIdx.x * 256 + threadIdx.x;
    if (i < E) atomicAdd(&count[esrc[i]], 1);
}

__global__ __launch_bounds__(256) void k_scan1(const int* __restrict__ count,
                                               int* __restrict__ bsum, int N) {
    __shared__ int s[256];
    int i = blockIdx.x * 256 + threadIdx.x;
    s[threadIdx.x] = (i < N) ? count[i] : 0;
    __syncthreads();
    #pragma unroll
    for (int off = 128; off > 0; off >>= 1) {
        if (threadIdx.x < off) s[threadIdx.x] += s[threadIdx.x + off];
        __syncthreads();
    }
    if (threadIdx.x == 0) bsum[blockIdx.x] = s[0];
}

__global__ __launch_bounds__(256) void k_scan2(const int* __restrict__ bsum,
                                               int* __restrict__ boff, int nb,
                                               int* __restrict__ baseN, int E) {
    __shared__ int s[256];
    const int t = threadIdx.x;
    int v = (t < nb) ? bsum[t] : 0;
    s[t] = v;
    __syncthreads();
    for (int off = 1; off < 256; off <<= 1) {
        int u = (t >= off) ? s[t - off] : 0;
        __syncthreads();
        s[t] += u;
        __syncthreads();
    }
    if (t < nb) boff[t] = s[t] - v;   // exclusive prefix of block sums
    if (t == 0) *baseN = E;
}

__global__ __launch_bounds__(256) void k_scan3(const int* __restrict__ count,
                                               const int* __restrict__ boff,
                                               int* __restrict__ base,
                                               int* __restrict__ cursor, int N) {
    __shared__ int s[256];
    const int t = threadIdx.x;
    int i = blockIdx.x * 256 + t;
    int v = (i < N) ? count[i] : 0;
    s[t] = v;
    __syncthreads();
    for (int off = 1; off < 256; off <<= 1) {
        int u = (t >= off) ? s[t - off] : 0;
        __syncthreads();
        s[t] += u;
        __syncthreads();
    }
    if (i < N) {
        int ex = boff[blockIdx.x] + s[t] - v;
        base[i] = ex; cursor[i] = ex;
    }
}

__global__ void k_scatter(const int* __restrict__ esrc, const int* __restrict__ edst,
                          int* __restrict__ cursor, int* __restrict__ sdst, int E) {
    int i = blockIdx.x * 256 + threadIdx.x;
    if (i < E) {
        int pos = atomicAdd(&cursor[esrc[i]], 1);
        sdst[pos] = edst[i];
    }
}

// ---------------------------------------------------------------------------
// Transpose W_A [H,N] f32 -> M [N,H] bf16
// ---------------------------------------------------------------------------
__global__ __launch_bounds__(256) void k_transpose(
    const float* __restrict__ WA, bf16* __restrict__ M, int N)
{
    __shared__ float t[128][65];
    const int n0  = blockIdx.x * 64;
    const int tid = threadIdx.x;
    const int w = tid >> 6, l = tid & 63;
    #pragma unroll
    for (int rep = 0; rep < 32; ++rep) {
        int hh = rep * 4 + w;
        int n  = n0 + l;
        t[hh][l] = (n < N) ? WA[(size_t)hh * N + n] : 0.f;
    }
    __syncthreads();
    #pragma unroll
    for (int rep = 0; rep < 32; ++rep) {
        int n_l = rep * 2 + (tid >> 7);
        int n   = n0 + n_l;
        if (n < N) M[(size_t)n * NH + (tid & 127)] = (bf16)t[tid & 127][n_l];
    }
}

// ---------------------------------------------------------------------------
// K3: A_x row-gather + fused finale. One wave per node; 16-lane x 4-edge
// dwordx4 gathers (4x fewer load instrs than dword-per-lane), 8 edges/iter.
// ---------------------------------------------------------------------------
__device__ __forceinline__ void add8(float* a, uint4 v) {
    a[0] += __uint_as_float(v.x << 16);  a[1] += __uint_as_float(v.x & 0xffff0000u);
    a[2] += __uint_as_float(v.y << 16);  a[3] += __uint_as_float(v.y & 0xffff0000u);
    a[4] += __uint_as_float(v.z << 16);  a[5] += __uint_as_float(v.z & 0xffff0000u);
    a[6] += __uint_as_float(v.w << 16);  a[7] += __uint_as_float(v.w & 0xffff0000u);
}

__global__ __launch_bounds__(256) void k_spmm_out(
    const bf16* __restrict__ Mb, const int* __restrict__ base,
    const int* __restrict__ sdst, const float* __restrict__ aggbuf,
    const float* __restrict__ bA, const float* __restrict__ Wend,
    const float* __restrict__ bend, float* __restrict__ out, int N)
{
    __shared__ float wend_s[NC][128];
    __shared__ float bend_s[NC];
    const int tid = threadIdx.x;
    for (int id = tid; id < NC * 128; id += 256) wend_s[id >> 7][id & 127] = Wend[id];
    if (tid < NC) bend_s[tid] = bend[tid];
    __syncthreads();

    const int w = tid >> 6, l = tid & 63;
    const int n = blockIdx.x * 4 + w;
    if (n >= N) return;
    const int e = l >> 4, q = l & 15;
    const unsigned short* Mu = (const unsigned short*)Mb;

    const int b0 = base[n], b1 = base[n + 1];
    float acc[8] = {0.f, 0.f, 0.f, 0.f, 0.f, 0.f, 0.f, 0.f};
    int j = b0;
    for (; j + 8 <= b1; j += 8) {
        int d0 = sdst[j + e];
        int d1 = sdst[j + 4 + e];
        uint4 v0 = *((const uint4*)(Mu + (size_t)d0 * NH) + q);
        uint4 v1 = *((const uint4*)(Mu + (size_t)d1 * NH) + q);
        add8(acc, v0); add8(acc, v1);
    }
    for (; j + 4 <= b1; j += 4) {
        int d0 = sdst[j + e];
        uint4 v0 = *((const uint4*)(Mu + (size_t)d0 * NH) + q);
        add8(acc, v0);
    }
    if (e < b1 - j) {
        int d0 = sdst[j + e];
        uint4 v0 = *((const uint4*)(Mu + (size_t)d0 * NH) + q);
        add8(acc, v0);
    }
    #pragma unroll
    for (int k = 0; k < 8; ++k) {
        acc[k] += __shfl_xor(acc[k], 16, 64);
        acc[k] += __shfl_xor(acc[k], 32, 64);
    }

    // epilogue: all lanes (4x redundant across e-groups), lane owns ch q*8..+7
    float4 agA = *(const float4*)&aggbuf[(size_t)n * NH + q * 8];
    float4 agB = *(const float4*)&aggbuf[(size_t)n * NH + q * 8 + 4];
    float4 bA0 = *(const float4*)&bA[q * 8];
    float4 bA1 = *(const float4*)&bA[q * 8 + 4];
    float gg[8];
    gg[0] = gelu_fast(agA.x + 0.5f * (acc[0] + bA0.x));
    gg[1] = gelu_fast(agA.y + 0.5f * (acc[1] + bA0.y));
    gg[2] = gelu_fast(agA.z + 0.5f * (acc[2] + bA0.z));
    gg[3] = gelu_fast(agA.w + 0.5f * (acc[3] + bA0.w));
    gg[4] = gelu_fast(agB.x + 0.5f * (acc[4] + bA1.x));
    gg[5] = gelu_fast(agB.y + 0.5f * (acc[5] + bA1.y));
    gg[6] = gelu_fast(agB.z + 0.5f * (acc[6] + bA1.z));
    gg[7] = gelu_fast(agB.w + 0.5f * (acc[7] + bA1.w));

    float part[NC];
    #pragma unroll
    for (int cc = 0; cc < NC; ++cc) {
        float p = 0.f;
        #pragma unroll
        for (int k = 0; k < 8; ++k) p += gg[k] * wend_s[cc][q * 8 + k];
        part[cc] = p;
    }
    #pragma unroll
    for (int off = 1; off < 16; off <<= 1)
        #pragma unroll
        for (int cc = 0; cc < NC; ++cc) part[cc] += __shfl_xor(part[cc], off, 64);

    float r = part[0];
    #pragma unroll
    for (int cc = 1; cc < NC; ++cc) r = (l == cc) ? part[cc] : r;
    if (l < NC) out[(size_t)n * NC + l] = r + bend_s[l];
}

// ---------------------------------------------------------------------------
extern "C" void kernel_launch(void* const* d_in, const int* in_sizes, int n_in,
                              void* d_out, int out_size, void* d_ws, size_t ws_size,
                              hipStream_t stream)
{
    const float* x     = (const float*)d_in[0];
    const float* Wproj = (const float*)d_in[1];
    const float* bproj = (const float*)d_in[2];
    const float* Wx    = (const float*)d_in[3];
    const float* bx    = (const float*)d_in[4];
    const float* Wpath = (const float*)d_in[5];
    const float* bpath = (const float*)d_in[6];
    const float* WA    = (const float*)d_in[7];
    const float* bA    = (const float*)d_in[8];
    const float* Wend  = (const float*)d_in[9];
    const float* bend  = (const float*)d_in[10];
    const int*   index = (const int*)d_in[11];
    const int*   eidx  = (const int*)d_in[12];

    const int N = in_sizes[0] / NF;
    const int E = in_sizes[12] / 2;
    const int* esrc = eidx;
    const int* edst = eidx + E;

    char* p = (char*)d_ws;
    auto alloc = [&](size_t bytes) {
        char* r = p;
        p += (bytes + 255) & ~(size_t)255;
        return r;
    };
    bf16*  pp     = (bf16*)alloc((size_t)N * NPH * sizeof(bf16));
    float* h      = (float*)alloc((size_t)N * NH * sizeof(float));
    float* aggbuf = (float*)alloc((size_t)N * NH * sizeof(float));
    bf16*  Mb     = (bf16*)alloc((size_t)N * NH * sizeof(bf16));
    int*   count  = (int*)alloc((size_t)N * sizeof(int));
    int*   base   = (int*)alloc((size_t)(N + 1) * sizeof(int));
    int*   cursor = (int*)alloc((size_t)N * sizeof(int));
    int*   sdst   = (int*)alloc((size_t)E * sizeof(int));
    int*   bsum   = (int*)alloc(512 * sizeof(int));
    int*   boff   = (int*)alloc(512 * sizeof(int));

    const int nb = (N + 255) / 256;

    hipMemsetAsync(count, 0, (size_t)N * sizeof(int), stream);
    k_hist<<<(E + 255) / 256, 256, 0, stream>>>(esrc, count, E);
    k_scan1<<<nb, 256, 0, stream>>>(count, bsum, N);
    k_scan2<<<1, 256, 0, stream>>>(bsum, boff, nb, base + N, E);
    k_scan3<<<nb, 256, 0, stream>>>(count, boff, base, cursor, N);
    k_scatter<<<(E + 255) / 256, 256, 0, stream>>>(esrc, edst, cursor, sdst, E);
    k_transpose<<<(N + 63) / 64, 256, 0, stream>>>(WA, Mb, N);
    k_proj<<<(N + 63) / 64, 256, 0, stream>>>(x, Wproj, bproj, Wx, bx, pp, h, N);
    const int nrounds = N / 4;
    k_path<<<1024, 256, 0, stream>>>(pp, h, Wpath, bpath, index, aggbuf, N, nrounds);
    k_spmm_out<<<(N + 3) / 4, 256, 0, stream>>>(Mb, base, sdst, aggbuf, bA, Wend, bend,
                                                (float*)d_out, N);
}

// Round 4
// 286.743 us; speedup vs baseline: 2.0636x; 1.5253x over previous
//
#include <hip/hip_runtime.h>
#include <hip/hip_bf16.h>
#include <math.h>

#define NF   128   // F
#define NPH  64    // PH
#define NP   8     // P
#define ND   4     // D
#define NH   128   // H
#define NC   10    // C

typedef __bf16 bf16;
typedef __attribute__((ext_vector_type(4))) __bf16 bf16x4;
typedef __attribute__((ext_vector_type(8))) __bf16 bf16x8;
typedef __attribute__((ext_vector_type(4))) float f32x4;

// fast exact-erf GELU: Abramowitz-Stegun 7.1.25 (3-term), |eps|<=2.5e-5
__device__ __forceinline__ float gelu_fast(float x) {
    float z = fabsf(x) * 0.70710678118654752f;
    float t = 1.0f / (1.0f + 0.47047f * z);
    float poly = t * (0.3480242f + t * (-0.0958798f + t * 0.7478556f));
    float erfv = 1.0f - poly * __expf(-z * z);
    float s = copysignf(erfv, x);
    return 0.5f * x * (1.0f + s);
}

#define GLOAD_LDS16(g, l)                                                     \
    __builtin_amdgcn_global_load_lds(                                         \
        (const __attribute__((address_space(1))) unsigned int*)(g),           \
        (__attribute__((address_space(3))) unsigned int*)(l), 16, 0, 0)

__device__ __forceinline__ bf16x8 cvt8(float4 a, float4 b) {
    bf16x8 r;
    r[0] = (bf16)a.x; r[1] = (bf16)a.y; r[2] = (bf16)a.z; r[3] = (bf16)a.w;
    r[4] = (bf16)b.x; r[5] = (bf16)b.y; r[6] = (bf16)b.z; r[7] = (bf16)b.w;
    return r;
}

// ---------------------------------------------------------------------------
// K1 (MFMA): pp = x@W_proj.T + b_proj (bf16); h = gelu(x@W_x.T + b_x) (f32)
// ---------------------------------------------------------------------------
__global__ __launch_bounds__(256) void k_proj(
    const float* __restrict__ x,
    const float* __restrict__ Wproj, const float* __restrict__ bproj,
    const float* __restrict__ Wx,    const float* __restrict__ bx,
    bf16* __restrict__ pp, float* __restrict__ h, int N)
{
    __shared__ alignas(16) bf16 x_s[64 * 136];
    const int tid = threadIdx.x;
    const int w = tid >> 6, l = tid & 63;
    const int c = l & 15, g = l >> 4;

    bf16x8 bfr[3][4];
    float bias[3];
    #pragma unroll
    for (int t = 0; t < 3; ++t) {
        int ch = (w * 3 + t) * 16 + c;
        const float* wr = (ch < NPH) ? &Wproj[(size_t)ch * NF]
                                     : &Wx[(size_t)(ch - NPH) * NF];
        bias[t] = (ch < NPH) ? bproj[ch] : bx[ch - NPH];
        #pragma unroll
        for (int ks = 0; ks < 4; ++ks) {
            const float* src = wr + ks * 32 + g * 8;
            bfr[t][ks] = cvt8(*(const float4*)src, *(const float4*)(src + 4));
        }
    }

    const int n0 = blockIdx.x * 64;
    #pragma unroll
    for (int rr = 0; rr < 8; ++rr) {
        int id  = rr * 256 + tid;        // 2048 float4 chunks: 64 rows x 32
        int row = id >> 5, c4 = id & 31;
        float4 v = make_float4(0.f, 0.f, 0.f, 0.f);
        if (n0 + row < N) v = *(const float4*)&x[(size_t)(n0 + row) * NF + c4 * 4];
        bf16x4 o;
        o[0] = (bf16)v.x; o[1] = (bf16)v.y; o[2] = (bf16)v.z; o[3] = (bf16)v.w;
        *(bf16x4*)&x_s[row * 136 + c4 * 4] = o;
    }
    __syncthreads();

    f32x4 acc[4][3] = {};
    #pragma unroll
    for (int rt = 0; rt < 4; ++rt)
        #pragma unroll
        for (int ks = 0; ks < 4; ++ks) {
            bf16x8 a = *(const bf16x8*)&x_s[(rt * 16 + c) * 136 + ks * 32 + g * 8];
            #pragma unroll
            for (int t = 0; t < 3; ++t)
                acc[rt][t] = __builtin_amdgcn_mfma_f32_16x16x32_bf16(
                    a, bfr[t][ks], acc[rt][t], 0, 0, 0);
        }

    #pragma unroll
    for (int rt = 0; rt < 4; ++rt) {
        #pragma unroll
        for (int t = 0; t < 3; ++t) {
            int ch = (w * 3 + t) * 16 + c;
            #pragma unroll
            for (int i = 0; i < 4; ++i) {
                int n = n0 + rt * 16 + g * 4 + i;
                if (n >= N) continue;
                float v = acc[rt][t][i] + bias[t];
                if (ch < NPH) pp[(size_t)n * NPH + ch] = (bf16)v;
                else          h[(size_t)n * NH + (ch - NPH)] = gelu_fast(v);
            }
        }
    }
}

// ---------------------------------------------------------------------------
// K2: per round = 4 nodes (32 path rows). Double-buffered, software-pipelined.
// ---------------------------------------------------------------------------
__global__ __launch_bounds__(256) void k_path(
    const bf16* __restrict__ pp, const float* __restrict__ h,
    const float* __restrict__ Wpath, const float* __restrict__ bpath,
    const int* __restrict__ index, float* __restrict__ aggbuf,
    int N, int nrounds)
{
    __shared__ alignas(16) bf16 path_s[2][32 * 256];  // swizzled content
    __shared__ alignas(16) float h_s[2][4][128];
    __shared__ float s_red[4][32];

    const int tid = threadIdx.x;
    const int w   = tid >> 6;
    const int l   = tid & 63;
    const int c   = l & 15;
    const int g   = l >> 4;
    const int nl  = g >> 1;            // local node (within a pair)
    const bool hi_half = (g & 1);

    // hoist B fragments (W_path cols for this wave's 2 h-tiles)
    bf16x8 bfrag[2][8];
    #pragma unroll
    for (int ht = 0; ht < 2; ++ht) {
        int hg = (w * 2 + ht) * 16 + c;
        #pragma unroll
        for (int ks = 0; ks < 8; ++ks) {
            const float* src = &Wpath[(size_t)hg * 256 + ks * 32 + g * 8];
            bfrag[ht][ks] = cvt8(*(const float4*)src, *(const float4*)(src + 4));
        }
    }
    const float bp0 = bpath[(w * 2 + 0) * 16 + c];
    const float bp1 = bpath[(w * 2 + 1) * 16 + c];

    auto stage = [&](int round, int b) {
        const int n0 = round * 4;
        #pragma unroll
        for (int rr = 0; rr < 4; ++rr) {
            int id  = rr * 256 + tid;
            int row = id >> 5;
            int cc  = id & 31;
            int ls  = cc ^ (row & 7);      // source-side swizzle
            int d   = ls >> 3, q = ls & 7;
            int nn  = row >> 3, p = row & 7;
            int idx = index[(size_t)(n0 + nn) * (NP * ND) + p * ND + d];
            GLOAD_LDS16(pp + (size_t)idx * NPH + q * 8, &path_s[b][id * 8]);
        }
        if (tid < 128) {
            int node = tid >> 5, q = tid & 31;
            GLOAD_LDS16(&h[(size_t)(n0 + node) * NH + q * 4], &h_s[b][node][q * 4]);
        }
    };

    int r = blockIdx.x;
    const int G = gridDim.x;
    if (r < nrounds) stage(r, 0);
    int buf = 0;

    for (; r < nrounds; r += G) {
        const int n0 = r * 4;
        __syncthreads();                        // round-r stage complete
        if (r + G < nrounds) stage(r + G, buf ^ 1);   // prefetch next round

        // MFMA: row-tile rt covers rows rt*16..rt*16+15 (pair rt)
        f32x4 acc[2][2] = {};
        #pragma unroll
        for (int rt = 0; rt < 2; ++rt) {
            const int rowbase = (rt * 16 + c) * 256;
            #pragma unroll
            for (int ks = 0; ks < 8; ++ks) {
                int chunk = (ks * 4 + g) ^ (c & 7);     // read-side XOR
                bf16x8 a = *(const bf16x8*)&path_s[buf][rowbase + chunk * 8];
                acc[rt][0] = __builtin_amdgcn_mfma_f32_16x16x32_bf16(
                    a, bfrag[0][ks], acc[rt][0], 0, 0, 0);
                acc[rt][1] = __builtin_amdgcn_mfma_f32_16x16x32_bf16(
                    a, bfrag[1][ks], acc[rt][1], 0, 0, 0);
            }
        }

        // epilogue part 1: pi = gelu(acc+b); partial scores -> s_red
        float pi[2][2][4];
        #pragma unroll
        for (int rt = 0; rt < 2; ++rt) {
            const float hv0 = h_s[buf][rt * 2 + nl][w * 32 + c];
            const float hv1 = h_s[buf][rt * 2 + nl][w * 32 + 16 + c];
            float sp[4];
            #pragma unroll
            for (int i = 0; i < 4; ++i) {
                pi[rt][0][i] = gelu_fast(acc[rt][0][i] + bp0);
                pi[rt][1][i] = gelu_fast(acc[rt][1][i] + bp1);
                sp[i] = hv0 * pi[rt][0][i] + hv1 * pi[rt][1][i];
            }
            #pragma unroll
            for (int off = 1; off < 16; off <<= 1)
                #pragma unroll
                for (int i = 0; i < 4; ++i) sp[i] += __shfl_xor(sp[i], off, 64);
            float v = (c == 0) ? sp[0] : (c == 1) ? sp[1] : (c == 2) ? sp[2] : sp[3];
            if (c < 4) s_red[w][rt * 16 + g * 4 + c] = v;
        }

        // raw barrier: drain LDS ops only, keep global_load_lds in flight
        __builtin_amdgcn_sched_barrier(0);
        asm volatile("s_waitcnt lgkmcnt(0)" ::: "memory");
        __builtin_amdgcn_s_barrier();
        __builtin_amdgcn_sched_barrier(0);

        // epilogue part 2: softmax (lane computes its own 4 rows + partner)
        #pragma unroll
        for (int rt = 0; rt < 2; ++rt) {
            float st[4];
            #pragma unroll
            for (int i = 0; i < 4; ++i) {
                int row = rt * 16 + g * 4 + i;
                st[i] = s_red[0][row] + s_red[1][row] +
                        s_red[2][row] + s_red[3][row];
            }
            float m4 = fmaxf(fmaxf(st[0], st[1]), fmaxf(st[2], st[3]));
            float m  = fmaxf(m4, __shfl_xor(m4, 16, 64));
            float e[4], s4 = 0.f;
            #pragma unroll
            for (int i = 0; i < 4; ++i) { e[i] = __expf(st[i] - m); s4 += e[i]; }
            float den = s4 + __shfl_xor(s4, 16, 64);
            const float inv = 1.0f / den;

            float pa0 = 0.f, pa1 = 0.f;
            #pragma unroll
            for (int i = 0; i < 4; ++i) {
                pa0 += e[i] * pi[rt][0][i];
                pa1 += e[i] * pi[rt][1][i];
            }
            pa0 = (pa0 + __shfl_xor(pa0, 16, 64)) * inv;
            pa1 = (pa1 + __shfl_xor(pa1, 16, 64)) * inv;

            if (!hi_half) {
                int n = n0 + rt * 2 + nl;
                const float hv0 = h_s[buf][rt * 2 + nl][w * 32 + c];
                const float hv1 = h_s[buf][rt * 2 + nl][w * 32 + 16 + c];
                aggbuf[(size_t)n * NH + w * 32 + c]      = 0.5f * (pa0 + hv0);
                aggbuf[(size_t)n * NH + w * 32 + 16 + c] = 0.5f * (pa1 + hv1);
            }
        }
        buf ^= 1;
    }
}

// ---------------------------------------------------------------------------
// Edge pipeline v2: bucketed counting sort (bucket = src>>8, <=256 nodes each)
//   k_bhist  : global bucket histogram
//   k_bscan  : scan bucket sizes -> gbase/gcur
//   k_bucket : per 2048-edge tile: LDS rank + 1 global atomic per bucket,
//              chunk-contiguous (src,dst) writes  -> no 16x write amplification
//   k_bsort  : per bucket: LDS hist+scan -> base[] coalesced; scatter sdst
//              within the bucket's contiguous region (L2 write-combined)
// ---------------------------------------------------------------------------
__global__ __launch_bounds__(256) void k_bhist(
    const int* __restrict__ esrc, int* __restrict__ bcnt, int E, int nbuck)
{
    __shared__ int hist[256];
    hist[threadIdx.x] = 0;
    __syncthreads();
    for (int i = blockIdx.x * 256 + threadIdx.x; i < E; i += gridDim.x * 256)
        atomicAdd(&hist[esrc[i] >> 8], 1);
    __syncthreads();
    if (threadIdx.x < nbuck && hist[threadIdx.x])
        atomicAdd(&bcnt[threadIdx.x], hist[threadIdx.x]);
}

__global__ __launch_bounds__(256) void k_bscan(
    const int* __restrict__ bcnt, int* __restrict__ gbase,
    int* __restrict__ gcur, int nbuck, int E)
{
    __shared__ int s[256];
    const int t = threadIdx.x;
    int v = (t < nbuck) ? bcnt[t] : 0;
    s[t] = v;
    __syncthreads();
    for (int off = 1; off < 256; off <<= 1) {
        int u = (t >= off) ? s[t - off] : 0;
        __syncthreads();
        s[t] += u;
        __syncthreads();
    }
    int ex = s[t] - v;
    if (t < nbuck) { gbase[t] = ex; gcur[t] = ex; }
    if (t == nbuck) gbase[t] = E;
}

__global__ __launch_bounds__(256) void k_bucket(
    const int* __restrict__ esrc, const int* __restrict__ edst,
    int* __restrict__ gcur, uint2* __restrict__ pairs, int E, int nbuck)
{
    __shared__ int cnt[256];
    __shared__ int bofs[256];
    const int tid = threadIdx.x;
    cnt[tid] = 0;
    __syncthreads();

    const int e0 = blockIdx.x * 2048;
    int src[8], dst[8], rk[8];
    #pragma unroll
    for (int k = 0; k < 8; ++k) {
        int i = e0 + k * 256 + tid;
        if (i < E) {
            src[k] = esrc[i]; dst[k] = edst[i];
            rk[k]  = atomicAdd(&cnt[src[k] >> 8], 1);
        } else src[k] = -1;
    }
    __syncthreads();
    if (tid < nbuck) {
        int cc = cnt[tid];
        bofs[tid] = cc ? atomicAdd(&gcur[tid], cc) : 0;
    }
    __syncthreads();
    #pragma unroll
    for (int k = 0; k < 8; ++k)
        if (src[k] >= 0)
            pairs[bofs[src[k] >> 8] + rk[k]] =
                make_uint2((unsigned)src[k], (unsigned)dst[k]);
}

__global__ __launch_bounds__(256) void k_bsort(
    const uint2* __restrict__ pairs, const int* __restrict__ gbase,
    int* __restrict__ sdst, int* __restrict__ base, int N, int E)
{
    __shared__ int hist[256], sc[256], cur[256];
    const int b = blockIdx.x, t = threadIdx.x;
    const int lo = gbase[b], hi = gbase[b + 1];
    hist[t] = 0;
    __syncthreads();
    for (int j = lo + t; j < hi; j += 256)
        atomicAdd(&hist[pairs[j].x & 255], 1);
    __syncthreads();
    int v = hist[t];
    sc[t] = v;
    __syncthreads();
    for (int off = 1; off < 256; off <<= 1) {
        int u = (t >= off) ? sc[t - off] : 0;
        __syncthreads();
        sc[t] += u;
        __syncthreads();
    }
    int ex = lo + sc[t] - v;
    cur[t] = ex;
    int n = b * 256 + t;
    if (n < N) base[n] = ex;
    if (b == 0 && t == 0) base[N] = E;
    __syncthreads();
    for (int j = lo + t; j < hi; j += 256) {
        uint2 p = pairs[j];
        int pos = atomicAdd(&cur[p.x & 255], 1);
        sdst[pos] = (int)p.y;
    }
}

// ---------------------------------------------------------------------------
// Transpose W_A [H,N] f32 -> M [N,H] bf16
// ---------------------------------------------------------------------------
__global__ __launch_bounds__(256) void k_transpose(
    const float* __restrict__ WA, bf16* __restrict__ M, int N)
{
    __shared__ float t[128][65];
    const int n0  = blockIdx.x * 64;
    const int tid = threadIdx.x;
    const int w = tid >> 6, l = tid & 63;
    #pragma unroll
    for (int rep = 0; rep < 32; ++rep) {
        int hh = rep * 4 + w;
        int n  = n0 + l;
        t[hh][l] = (n < N) ? WA[(size_t)hh * N + n] : 0.f;
    }
    __syncthreads();
    #pragma unroll
    for (int rep = 0; rep < 32; ++rep) {
        int n_l = rep * 2 + (tid >> 7);
        int n   = n0 + n_l;
        if (n < N) M[(size_t)n * NH + (tid & 127)] = (bf16)t[tid & 127][n_l];
    }
}

// ---------------------------------------------------------------------------
// K3: A_x row-gather + fused finale. One wave per node; 16-lane x 4-edge
// dwordx4 gathers, 16 edges/iter (4 outstanding rows per lane-group).
// ---------------------------------------------------------------------------
__device__ __forceinline__ void add8(float* a, uint4 v) {
    a[0] += __uint_as_float(v.x << 16);  a[1] += __uint_as_float(v.x & 0xffff0000u);
    a[2] += __uint_as_float(v.y << 16);  a[3] += __uint_as_float(v.y & 0xffff0000u);
    a[4] += __uint_as_float(v.z << 16);  a[5] += __uint_as_float(v.z & 0xffff0000u);
    a[6] += __uint_as_float(v.w << 16);  a[7] += __uint_as_float(v.w & 0xffff0000u);
}

__global__ __launch_bounds__(256) void k_spmm_out(
    const bf16* __restrict__ Mb, const int* __restrict__ base,
    const int* __restrict__ sdst, const float* __restrict__ aggbuf,
    const float* __restrict__ bA, const float* __restrict__ Wend,
    const float* __restrict__ bend, float* __restrict__ out, int N)
{
    __shared__ float wend_s[NC][128];
    __shared__ float bend_s[NC];
    const int tid = threadIdx.x;
    for (int id = tid; id < NC * 128; id += 256) wend_s[id >> 7][id & 127] = Wend[id];
    if (tid < NC) bend_s[tid] = bend[tid];
    __syncthreads();

    const int w = tid >> 6, l = tid & 63;
    const int n = blockIdx.x * 4 + w;
    if (n >= N) return;
    const int e = l >> 4, q = l & 15;
    const unsigned short* Mu = (const unsigned short*)Mb;

    const int b0 = base[n], b1 = base[n + 1];
    float acc[8] = {0.f, 0.f, 0.f, 0.f, 0.f, 0.f, 0.f, 0.f};
    int j = b0;
    for (; j + 16 <= b1; j += 16) {
        int d0 = sdst[j + e];
        int d1 = sdst[j + 4 + e];
        int d2 = sdst[j + 8 + e];
        int d3 = sdst[j + 12 + e];
        uint4 v0 = *((const uint4*)(Mu + (size_t)d0 * NH) + q);
        uint4 v1 = *((const uint4*)(Mu + (size_t)d1 * NH) + q);
        uint4 v2 = *((const uint4*)(Mu + (size_t)d2 * NH) + q);
        uint4 v3 = *((const uint4*)(Mu + (size_t)d3 * NH) + q);
        add8(acc, v0); add8(acc, v1); add8(acc, v2); add8(acc, v3);
    }
    for (; j + 4 <= b1; j += 4) {
        int d0 = sdst[j + e];
        uint4 v0 = *((const uint4*)(Mu + (size_t)d0 * NH) + q);
        add8(acc, v0);
    }
    if (e < b1 - j) {
        int d0 = sdst[j + e];
        uint4 v0 = *((const uint4*)(Mu + (size_t)d0 * NH) + q);
        add8(acc, v0);
    }
    #pragma unroll
    for (int k = 0; k < 8; ++k) {
        acc[k] += __shfl_xor(acc[k], 16, 64);
        acc[k] += __shfl_xor(acc[k], 32, 64);
    }

    // epilogue: all lanes (4x redundant across e-groups), lane owns ch q*8..+7
    float4 agA = *(const float4*)&aggbuf[(size_t)n * NH + q * 8];
    float4 agB = *(const float4*)&aggbuf[(size_t)n * NH + q * 8 + 4];
    float4 bA0 = *(const float4*)&bA[q * 8];
    float4 bA1 = *(const float4*)&bA[q * 8 + 4];
    float gg[8];
    gg[0] = gelu_fast(agA.x + 0.5f * (acc[0] + bA0.x));
    gg[1] = gelu_fast(agA.y + 0.5f * (acc[1] + bA0.y));
    gg[2] = gelu_fast(agA.z + 0.5f * (acc[2] + bA0.z));
    gg[3] = gelu_fast(agA.w + 0.5f * (acc[3] + bA0.w));
    gg[4] = gelu_fast(agB.x + 0.5f * (acc[4] + bA1.x));
    gg[5] = gelu_fast(agB.y + 0.5f * (acc[5] + bA1.y));
    gg[6] = gelu_fast(agB.z + 0.5f * (acc[6] + bA1.z));
    gg[7] = gelu_fast(agB.w + 0.5f * (acc[7] + bA1.w));

    float part[NC];
    #pragma unroll
    for (int cc = 0; cc < NC; ++cc) {
        float p = 0.f;
        #pragma unroll
        for (int k = 0; k < 8; ++k) p += gg[k] * wend_s[cc][q * 8 + k];
        part[cc] = p;
    }
    #pragma unroll
    for (int off = 1; off < 16; off <<= 1)
        #pragma unroll
        for (int cc = 0; cc < NC; ++cc) part[cc] += __shfl_xor(part[cc], off, 64);

    float r = part[0];
    #pragma unroll
    for (int cc = 1; cc < NC; ++cc) r = (l == cc) ? part[cc] : r;
    if (l < NC) out[(size_t)n * NC + l] = r + bend_s[l];
}

// ---------------------------------------------------------------------------
extern "C" void kernel_launch(void* const* d_in, const int* in_sizes, int n_in,
                              void* d_out, int out_size, void* d_ws, size_t ws_size,
                              hipStream_t stream)
{
    const float* x     = (const float*)d_in[0];
    const float* Wproj = (const float*)d_in[1];
    const float* bproj = (const float*)d_in[2];
    const float* Wx    = (const float*)d_in[3];
    const float* bx    = (const float*)d_in[4];
    const float* Wpath = (const float*)d_in[5];
    const float* bpath = (const float*)d_in[6];
    const float* WA    = (const float*)d_in[7];
    const float* bA    = (const float*)d_in[8];
    const float* Wend  = (const float*)d_in[9];
    const float* bend  = (const float*)d_in[10];
    const int*   index = (const int*)d_in[11];
    const int*   eidx  = (const int*)d_in[12];

    const int N = in_sizes[0] / NF;
    const int E = in_sizes[12] / 2;
    const int* esrc = eidx;
    const int* edst = eidx + E;
    const int nbuck = (N + 255) >> 8;

    char* p = (char*)d_ws;
    auto alloc = [&](size_t bytes) {
        char* r = p;
        p += (bytes + 255) & ~(size_t)255;
        return r;
    };
    bf16*  pp     = (bf16*)alloc((size_t)N * NPH * sizeof(bf16));
    float* h      = (float*)alloc((size_t)N * NH * sizeof(float));
    float* aggbuf = (float*)alloc((size_t)N * NH * sizeof(float));
    bf16*  Mb     = (bf16*)alloc((size_t)N * NH * sizeof(bf16));
    int*   base   = (int*)alloc((size_t)(N + 1) * sizeof(int));
    int*   sdst   = (int*)alloc((size_t)E * sizeof(int));
    int*   bcnt   = (int*)alloc(256 * sizeof(int));
    int*   gbase  = (int*)alloc(257 * sizeof(int));
    int*   gcur   = (int*)alloc(256 * sizeof(int));
    uint2* pairs  = (uint2*)alloc((size_t)E * sizeof(uint2));

    hipMemsetAsync(bcnt, 0, 256 * sizeof(int), stream);
    k_bhist<<<256, 256, 0, stream>>>(esrc, bcnt, E, nbuck);
    k_bscan<<<1, 256, 0, stream>>>(bcnt, gbase, gcur, nbuck, E);
    k_bucket<<<(E + 2047) / 2048, 256, 0, stream>>>(esrc, edst, gcur, pairs, E, nbuck);
    k_bsort<<<nbuck, 256, 0, stream>>>(pairs, gbase, sdst, base, N, E);
    k_transpose<<<(N + 63) / 64, 256, 0, stream>>>(WA, Mb, N);
    k_proj<<<(N + 63) / 64, 256, 0, stream>>>(x, Wproj, bproj, Wx, bx, pp, h, N);
    const int nrounds = N / 4;
    k_path<<<1024, 256, 0, stream>>>(pp, h, Wpath, bpath, index, aggbuf, N, nrounds);
    k_spmm_out<<<(N + 3) / 4, 256, 0, stream>>>(Mb, base, sdst, aggbuf, bA, Wend, bend,
                                                (float*)d_out, N);
}